// Round 7
// baseline (134.328 us; speedup 1.0000x reference)
//
#include <hip/hip_runtime.h>

#define NCHAN 30
#define GPB   4      // row-groups (256 rows) per block -> 512 blocks = 2/CU, 8 waves/CU

// FILTERS baked as per-channel 6-bit masks: bit g = FILTERS[g][c]
__constant__ int FMASK_C[NCHAN] = {63,63,33,33,21,5,33,33,5,5,33,33,5,5,9,9,
                                   11,11,11,11,11,11,0,0,2,2,10,10,63,63};

typedef float f32x4 __attribute__((ext_vector_type(4)));

__global__ __launch_bounds__(256) void ext_kernel(
    const float* __restrict__ tpl,
    const float* __restrict__ cons,
    const float* __restrict__ w_gas,
    const float* __restrict__ W1, const float* __restrict__ b1,
    const float* __restrict__ W2, const float* __restrict__ b2,
    const float* __restrict__ W3, const float* __restrict__ b3,
    const float* __restrict__ Wo, const float* __restrict__ bo,
    f32x4* __restrict__ out4)
{
    __shared__ float p_lds[GPB][256][8];   // 32 KB: all folded rows for this block
    __shared__ float E_lds[32][8];         // E[c][k] = masked exp(w_gas[k][c])

    const int tid = threadIdx.x;

    if (tid < 8 * NCHAN) {
        const int c = tid >> 3, k = tid & 7;
        float e = __expf(w_gas[k * NCHAN + c]);       // w_gas is (8, 30) row-major
        if (k >= 2 && !((FMASK_C[c] >> (k - 2)) & 1)) e = 0.f;
        E_lds[c][k] = e;
    }

    const float4* c4 = (const float4*)cons;
    const int row0 = blockIdx.x * (GPB * 256) + tid;

    // ---- phase 1: MLP for all GPB groups (software-pipelined input loads) ----
    float4 ca = c4[(size_t)row0 * 2];
    float4 cb = c4[(size_t)row0 * 2 + 1];
    float t0  = tpl[(size_t)row0 * 3 + 0];
    float t1  = tpl[(size_t)row0 * 3 + 1];

    #pragma unroll
    for (int j = 0; j < GPB; ++j) {
        float4 nca, ncb; float nt0, nt1;
        if (j + 1 < GPB) {
            const int nrow = row0 + (j + 1) * 256;
            nca = c4[(size_t)nrow * 2];
            ncb = c4[(size_t)nrow * 2 + 1];
            nt0 = tpl[(size_t)nrow * 3 + 0];
            nt1 = tpl[(size_t)nrow * 3 + 1];
        }

        float s[6];
        #pragma unroll
        for (int g = 0; g < 6; ++g) {
            float h1[6], h2[4], h3[4];
            #pragma unroll
            for (int jj = 0; jj < 6; ++jj)
                h1[jj] = fmaxf(0.f, fmaf(W1[g*12 + jj*2], t0,
                               fmaf(W1[g*12 + jj*2 + 1], t1, b1[g*6 + jj])));
            #pragma unroll
            for (int o = 0; o < 4; ++o) {
                float a = b2[g*4 + o];
                #pragma unroll
                for (int jj = 0; jj < 6; ++jj) a = fmaf(W2[g*24 + o*6 + jj], h1[jj], a);
                h2[o] = fmaxf(0.f, a);
            }
            #pragma unroll
            for (int p = 0; p < 4; ++p) {
                float a = b3[g*4 + p];
                #pragma unroll
                for (int o = 0; o < 4; ++o) a = fmaf(W3[g*16 + p*4 + o], h2[o], a);
                h3[p] = fmaxf(0.f, a);
            }
            float a = bo[g];
            #pragma unroll
            for (int p = 0; p < 4; ++p) a = fmaf(Wo[g*4 + p], h3[p], a);
            s[g] = __fdividef(1.f, 1.f + __expf(-a));
        }

        float4 pa, pb;
        pa.x = ca.x;        pa.y = ca.y;
        pa.z = ca.z * s[0]; pa.w = ca.w * s[1];
        pb.x = cb.x * s[2]; pb.y = cb.y * s[3];
        pb.z = cb.z * s[4]; pb.w = cb.w * s[5];
        *(float4*)&p_lds[j][tid][0] = pa;
        *(float4*)&p_lds[j][tid][4] = pb;

        ca = nca; cb = ncb; t0 = nt0; t1 = nt1;
    }

    __syncthreads();   // the ONLY barrier: store stream below is never drained

    // ---- phase 2: uninterrupted 960 KB sequential store stream (240 stores/thread) ----
    const size_t gbase = (size_t)blockIdx.x * (GPB * 256 * NCHAN * 2);
    for (int j = 0; j < GPB; ++j) {
        const float (* __restrict__ pl)[8] = p_lds[j];
        const size_t jb = gbase + (size_t)j * (256 * NCHAN * 2);
        #pragma unroll 6
        for (int i = 0; i < 60; ++i) {
            const unsigned ch  = (unsigned)(i * 256 + tid);
            const unsigned nl  = ch / 60u;                // magic-mul
            const unsigned rem = ch - nl * 60u;           // c*2 + hi
            const unsigned hi4 = (rem & 1u) << 2;

            const float4 pv = *(const float4*)&pl[nl][hi4];
            const float4 ev = *(const float4*)&E_lds[rem >> 1][hi4];

            f32x4 v;
            v.x = pv.x * ev.x;
            v.y = pv.y * ev.y;
            v.z = pv.z * ev.z;
            v.w = pv.w * ev.w;
            __builtin_nontemporal_store(v, &out4[jb + ch]);
        }
    }
}

extern "C" void kernel_launch(void* const* d_in, const int* in_sizes, int n_in,
                              void* d_out, int out_size, void* d_ws, size_t ws_size,
                              hipStream_t stream) {
    const float* tpl  = (const float*)d_in[0];
    const float* cons = (const float*)d_in[1];
    const float* wgas = (const float*)d_in[2];
    const float* W1   = (const float*)d_in[3];
    const float* b1   = (const float*)d_in[4];
    const float* W2   = (const float*)d_in[5];
    const float* b2   = (const float*)d_in[6];
    const float* W3   = (const float*)d_in[7];
    const float* b3   = (const float*)d_in[8];
    const float* Wo   = (const float*)d_in[9];
    const float* bo   = (const float*)d_in[10];

    const int nrows  = in_sizes[0] / 3;          // 524288
    const int blocks = nrows / (256 * GPB);      // 512 blocks -> 2 per CU, 8 waves/CU

    ext_kernel<<<dim3(blocks), dim3(256), 0, stream>>>(
        tpl, cons, wgas, W1, b1, W2, b2, W3, b3, Wo, bo, (f32x4*)d_out);
}

// Round 8
// 103.298 us; speedup vs baseline: 1.3004x; 1.3004x over previous
//
#include <hip/hip_runtime.h>

#define NCHAN 30

// FILTERS baked as per-channel 6-bit masks: bit g = FILTERS[g][c]
__constant__ int FMASK_C[NCHAN] = {63,63,33,33,21,5,33,33,5,5,33,33,5,5,9,9,
                                   11,11,11,11,11,11,0,0,2,2,10,10,63,63};

typedef float f32x4 __attribute__((ext_vector_type(4)));

__global__ __launch_bounds__(256) void ext_kernel(
    const float* __restrict__ tpl,
    const float* __restrict__ cons,
    const float* __restrict__ w_gas,
    const float* __restrict__ W1, const float* __restrict__ b1,
    const float* __restrict__ W2, const float* __restrict__ b2,
    const float* __restrict__ W3, const float* __restrict__ b3,
    const float* __restrict__ Wo, const float* __restrict__ bo,
    f32x4* __restrict__ out4)
{
    __shared__ float p_lds[256][8];   // folded rows: cons * (1,1,s0..s5)
    __shared__ float E_lds[32][8];    // E[c][k] = masked exp(w_gas[k][c])

    const int tid = threadIdx.x;
    const int n   = blockIdx.x * 256 + tid;

    if (tid < 8 * NCHAN) {
        const int c = tid >> 3, k = tid & 7;
        float e = __expf(w_gas[k * NCHAN + c]);       // w_gas is (8, 30) row-major
        if (k >= 2 && !((FMASK_C[c] >> (k - 2)) & 1)) e = 0.f;
        E_lds[c][k] = e;
    }

    // ---- per-row MLP: t_p(2) -> 6 -> 4 -> 4 -> sigmoid, 6 groups ----
    const float4* c4 = (const float4*)cons;
    const float4 ca = c4[(size_t)n * 2];
    const float4 cb = c4[(size_t)n * 2 + 1];
    const float t0 = tpl[(size_t)n * 3 + 0];
    const float t1 = tpl[(size_t)n * 3 + 1];

    float s[6];
    #pragma unroll
    for (int g = 0; g < 6; ++g) {
        float h1[6], h2[4], h3[4];
        #pragma unroll
        for (int j = 0; j < 6; ++j)
            h1[j] = fmaxf(0.f, fmaf(W1[g*12 + j*2], t0,
                           fmaf(W1[g*12 + j*2 + 1], t1, b1[g*6 + j])));
        #pragma unroll
        for (int o = 0; o < 4; ++o) {
            float a = b2[g*4 + o];
            #pragma unroll
            for (int j = 0; j < 6; ++j) a = fmaf(W2[g*24 + o*6 + j], h1[j], a);
            h2[o] = fmaxf(0.f, a);
        }
        #pragma unroll
        for (int p = 0; p < 4; ++p) {
            float a = b3[g*4 + p];
            #pragma unroll
            for (int o = 0; o < 4; ++o) a = fmaf(W3[g*16 + p*4 + o], h2[o], a);
            h3[p] = fmaxf(0.f, a);
        }
        float a = bo[g];
        #pragma unroll
        for (int p = 0; p < 4; ++p) a = fmaf(Wo[g*4 + p], h3[p], a);
        s[g] = __fdividef(1.f, 1.f + __expf(-a));
    }

    float4 pa, pb;
    pa.x = ca.x;        pa.y = ca.y;
    pa.z = ca.z * s[0]; pa.w = ca.w * s[1];
    pb.x = cb.x * s[2]; pb.y = cb.y * s[3];
    pb.z = cb.z * s[4]; pb.w = cb.w * s[5];
    *(float4*)&p_lds[tid][0] = pa;
    *(float4*)&p_lds[tid][4] = pb;

    __syncthreads();

    // ---- emit: wave-per-64-rows, lane = chunk-in-row. E in REGISTERS,
    //      p via wave-uniform broadcast ds_read, stores address-incremental. ----
    const int lane = tid & 63;
    const int wid  = tid >> 6;

    const int erem = (lane < 60) ? lane : 0;          // rem = c*2 + hi
    const float4 ev = *(const float4*)&E_lds[erem >> 1][(erem & 1) << 2];
    const unsigned hi4 = (unsigned)(lane & 1) << 2;

    const size_t gbase = (size_t)blockIdx.x * (256 * NCHAN * 2);

    if (lane < 60) {
        const int r0 = wid * 64;                      // 64 rows per wave
        #pragma unroll 4
        for (int r = 0; r < 64; ++r) {
            const int nl = r0 + r;
            const float4 pv = *(const float4*)&p_lds[nl][hi4];  // broadcast read

            f32x4 v;
            v.x = pv.x * ev.x;
            v.y = pv.y * ev.y;
            v.z = pv.z * ev.z;
            v.w = pv.w * ev.w;
            __builtin_nontemporal_store(v, &out4[gbase + (size_t)nl * 60 + lane]);
        }
    }
}

extern "C" void kernel_launch(void* const* d_in, const int* in_sizes, int n_in,
                              void* d_out, int out_size, void* d_ws, size_t ws_size,
                              hipStream_t stream) {
    const float* tpl  = (const float*)d_in[0];
    const float* cons = (const float*)d_in[1];
    const float* wgas = (const float*)d_in[2];
    const float* W1   = (const float*)d_in[3];
    const float* b1   = (const float*)d_in[4];
    const float* W2   = (const float*)d_in[5];
    const float* b2   = (const float*)d_in[6];
    const float* W3   = (const float*)d_in[7];
    const float* b3   = (const float*)d_in[8];
    const float* Wo   = (const float*)d_in[9];
    const float* bo   = (const float*)d_in[10];

    const int nrows  = in_sizes[0] / 3;          // 524288
    const int blocks = nrows / 256;              // 2048

    ext_kernel<<<dim3(blocks), dim3(256), 0, stream>>>(
        tpl, cons, wgas, W1, b1, W2, b2, W3, b3, Wo, bo, (f32x4*)d_out);
}